// Round 8
// baseline (237.474 us; speedup 1.0000x reference)
//
#include <hip/hip_runtime.h>
#include <hip/hip_bf16.h>
#include <stdint.h>
#include <stddef.h>

// DCNv2 forward: B=4, H=W=96, C=256, F=256, K=9 (3x3, same, stride1, dil1), DG=1.
// R5/R8/R11: fusion failed 3x. R7: swizzle (conflicts->0). R9: XCD swizzle (-5us).
// R10: counted-vmcnt regressed. R12: atomic-free k_omgemm (-9us) -> 213us best.
// R13: full-N k_gemm regressed (FETCH flat at 90MB -> N-split never was the mechanism;
//   B-restage 679MB + worse density). k_gemm micro-opts now 0-for-5; only STRUCTURAL
//   traffic changes have ever won here.
// R14: chunked producer->consumer. px-space split in 2 chunks of 18432; ONE aliased
//   85MB cols buffer; ks(0) kg(0) ks(1) kg(1). Working set ~110MB < L3 256MB ->
//   kg reads L3-hot cols; ks(1) overwrites dirty L3 lines before eviction ->
//   ~260MB of HBM round-trip vanishes. kg tile 64x128, grid (288,2)=576=2.25/CU,
//   ks/kg XCD px-partitions matched. k_pad+k_wprep re-merged.

namespace {
constexpr int H  = 96, W = 96, C = 256, F = 256;
constexpr int HP = 98;            // padded spatial dim (1-px zero halo)
constexpr int NP = 4 * 96 * 96;   // 36864 output pixels
constexpr int KC = 9 * 256;       // 2304 = GEMM K
constexpr int NPC = NP / 2;       // 18432 px per chunk

constexpr int NB_PAD  = 4 * HP * HP / 8;       // 4802 blocks, 8 px each
constexpr int NB_OMW  = 9 * 32;                // 288
constexpr int NB_WT   = (KC / 64) * (F / 64);  // 144
}

typedef __attribute__((ext_vector_type(8))) short bf16x8;
typedef __attribute__((ext_vector_type(4))) float floatx4;

__device__ __forceinline__ void load_lds16(const void* g, void* l) {
  __builtin_amdgcn_global_load_lds((const __attribute__((address_space(1))) void*)g,
                                   (__attribute__((address_space(3))) void*)l,
                                   16, 0, 0);
}

__device__ __forceinline__ uint32_t pk2(float lo, float hi) {   // v_cvt_pk_bf16_f32 (RNE)
  __hip_bfloat162 t = __float22bfloat162_rn(float2{lo, hi});
  return *reinterpret_cast<uint32_t*>(&t);
}

__device__ __forceinline__ void acc8(uint4 v, float w, float* a) {
  a[0] += w * __uint_as_float(v.x << 16); a[1] += w * __uint_as_float(v.x & 0xffff0000u);
  a[2] += w * __uint_as_float(v.y << 16); a[3] += w * __uint_as_float(v.y & 0xffff0000u);
  a[4] += w * __uint_as_float(v.z << 16); a[5] += w * __uint_as_float(v.z & 0xffff0000u);
  a[6] += w * __uint_as_float(v.w << 16); a[7] += w * __uint_as_float(v.w & 0xffff0000u);
}

// ---------------- k_prep: pad + omw repack + wt transpose (one dispatch) ----------------
__global__ __launch_bounds__(256) void k_prep(const float* __restrict__ x,
                                              const float* __restrict__ omk,
                                              const float* __restrict__ kern,
                                              uint4* __restrict__ xp4,
                                              __hip_bfloat16* __restrict__ wom,
                                              __hip_bfloat16* __restrict__ wt) {
  __shared__ float t[64][65];
  const int bi = blockIdx.x, tid = threadIdx.x;

  if (bi < NB_PAD) {                       // ---- pad: 8 px/block, 8 ch/thread ----
    const int sub = tid >> 5, cid = tid & 31;
    const int pp  = bi * 8 + sub;
    const int b   = pp / (HP * HP);
    const int r   = pp % (HP * HP);
    const int y   = r / HP, xq = r % HP;
    uint4 o = {0u, 0u, 0u, 0u};
    if (y >= 1 && y <= H && xq >= 1 && xq <= W) {
      const float* src = x + ((size_t)((b * H + (y - 1)) * W + (xq - 1))) * C + cid * 8;
      const float4 v0 = *(const float4*)src;
      const float4 v1 = *(const float4*)(src + 4);
      o.x = pk2(v0.x, v0.y); o.y = pk2(v0.z, v0.w);
      o.z = pk2(v1.x, v1.y); o.w = pk2(v1.z, v1.w);
    }
    xp4[(size_t)pp * 32 + cid] = o;
  } else if (bi < NB_PAD + NB_OMW) {       // ---- omw: [9*256][27] -> [32][2304] ----
    const int i  = bi - NB_PAD;
    const int kk = i / 32, oc = i % 32;
    float v = (oc < 27) ? omk[(size_t)(kk * 256 + tid) * 27 + oc] : 0.f;
    wom[(size_t)oc * KC + kk * 256 + tid] = __float2bfloat16(v);
  } else {                                 // ---- wt: [KC][F] -> [F][KC] bf16 ----
    const int j   = bi - NB_PAD - NB_OMW;
    const int kc0 = (j % (KC / 64)) * 64, f0 = (j / (KC / 64)) * 64;
    const int rr = tid >> 6, cc = tid & 63;
#pragma unroll
    for (int i = 0; i < 16; ++i)
      t[rr * 16 + i][cc] = kern[(size_t)(kc0 + rr * 16 + i) * F + f0 + cc];
    __syncthreads();
#pragma unroll
    for (int i = 0; i < 16; ++i) {
      const int frow = rr * 16 + i;
      wt[(size_t)(f0 + frow) * KC + kc0 + cc] = __float2bfloat16(t[cc][frow]);
    }
  }
}

// ---------------- k_omgemm: implicit-im2col MFMA GEMM, 64(M)x32(N), full K, no atomics ----
__global__ __launch_bounds__(256) void k_omgemm(const __hip_bfloat16* __restrict__ xp,
                                                const __hip_bfloat16* __restrict__ wom,
                                                float* __restrict__ pOm) {
  __shared__ __align__(16) char lds[12288];   // 2 x {A [64][32] 4KB, B [32][32] 2KB}
  const int tid  = threadIdx.x;
  const int xr   = blockIdx.x;
  const int xs   = (xr & 7) * 72 + (xr >> 3);     // XCD-contiguous over 576 tiles
  const int m0   = xs * 64;
  const int lane = tid & 63, wave = tid >> 6;
  const int quad = lane >> 4, l16 = lane & 15;

  const int kp  = (tid & 3) ^ ((tid >> 3) & 3);
  const int row = tid >> 2;
  const int p  = m0 + row;
  const int b  = p / (H * W);
  const int hw = p % (H * W);
  const int h  = hw / W, w = hw % W;
  const __hip_bfloat16* abase = xp + ((size_t)(b * HP + h) * HP + w) * C + kp * 8;
  const __hip_bfloat16* bbase = wom + (size_t)row * KC + kp * 8;   // valid for tid<128

  auto stage = [&](int buf, int k0) {
    const int kk = k0 >> 8, c0 = k0 & 255;
    const int aoff = ((kk / 3) * HP + (kk % 3)) * C + c0;
    char* base = &lds[buf * 6144];
    load_lds16(abase + aoff, base + tid * 16);
    if (tid < 128) load_lds16(bbase + k0, base + 4096 + tid * 16);
  };

  floatx4 acc[2];
  acc[0] = (floatx4){0.f, 0.f, 0.f, 0.f};
  acc[1] = (floatx4){0.f, 0.f, 0.f, 0.f};

  const int swq = (quad ^ ((l16 >> 1) & 3)) * 16;

  stage(0, 0);
  int cur = 0;
#pragma unroll 1
  for (int k0 = 0; k0 < KC; k0 += 32) {
    __syncthreads();                       // drains stage issued last iter (or prologue)
    if (k0 + 32 < KC) stage(cur ^ 1, k0 + 32);
    const char* base = &lds[cur * 6144];

    bf16x8 af = *(const bf16x8*)&base[(wave * 16 + l16) * 64 + swq];
    bf16x8 b0 = *(const bf16x8*)&base[4096 + (l16) * 64 + swq];
    bf16x8 b1 = *(const bf16x8*)&base[4096 + (16 + l16) * 64 + swq];
    acc[0] = __builtin_amdgcn_mfma_f32_16x16x32_bf16(af, b0, acc[0], 0, 0, 0);
    acc[1] = __builtin_amdgcn_mfma_f32_16x16x32_bf16(af, b1, acc[1], 0, 0, 0);
    cur ^= 1;
  }

#pragma unroll
  for (int nt = 0; nt < 2; ++nt) {
    const int gm = m0 + wave * 16 + quad * 4;
    const int gn = nt * 16 + l16;
#pragma unroll
    for (int r = 0; r < 4; ++r)
      pOm[(size_t)(gm + r) * 32 + gn] = acc[nt][r];
  }
}

// ---------------- k_sample: one px-chunk; writes chunk-local cols (aliased buffer) ----------
__global__ __launch_bounds__(256) void k_sample(const uint4* __restrict__ xp4,
                                                const float* __restrict__ pOm,
                                                const float* __restrict__ om_bias,
                                                uint4* __restrict__ cols4,
                                                int p_base) {
  __shared__ float2 s_ow[8][9][4];   // per (px,k,corner): {uint4-offset, weight*mask}

  const int tid = threadIdx.x;
  const int sub = tid >> 5, cid = tid & 31;     // px-in-block, 8-ch unit
  const int bs  = (blockIdx.x & 7) * 288 + (blockIdx.x >> 3);   // XCD-contiguous in chunk

  if (tid < 72) {                               // setup: 8 px x 9 k
    const int ps = tid / 9, k = tid % 9;
    const int p  = p_base + bs * 8 + ps;
    const int b  = p / (H * W);
    const int hw = p % (H * W);
    const int h = hw / W, w = hw % W;
    const float dy = om_bias[2 * k]     + pOm[(size_t)p * 32 + 2 * k];
    const float dx = om_bias[2 * k + 1] + pOm[(size_t)p * 32 + 2 * k + 1];
    const float mv = om_bias[18 + k]    + pOm[(size_t)p * 32 + 18 + k];
    const float m  = 2.f / (1.f + __expf(-mv));
    const float sy = (float)(h - 1 + k / 3) + dy;
    const float sx = (float)(w - 1 + k % 3) + dx;
    const float y0f = floorf(sy), x0f = floorf(sx);
    const float fy = sy - y0f, fx = sx - x0f;
    const int y0 = (int)y0f, x0 = (int)x0f;
#pragma unroll
    for (int c2 = 0; c2 < 4; ++c2) {
      const int dy2 = c2 >> 1, dx2 = c2 & 1;
      const int yi = y0 + dy2, xi = x0 + dx2;
      const bool valid = (yi >= 0) & (yi < H) & (xi >= 0) & (xi < W);
      const float wgt = valid ? (dy2 ? fy : 1.f - fy) * (dx2 ? fx : 1.f - fx) * m : 0.f;
      const int yc = min(max(yi + 1, 0), HP - 1);
      const int xc = min(max(xi + 1, 0), HP - 1);
      const int off = ((b * HP + yc) * HP + xc) * 32;   // uint4 units
      s_ow[ps][k][c2] = float2{__int_as_float(off), wgt};
    }
  }
  __syncthreads();

  const int lp = bs * 8 + sub;                  // chunk-local row
  uint4* __restrict__ ob = cols4 + (size_t)lp * 288 + cid;   // KC bf16 = 288 uint4/row

#pragma unroll 1
  for (int k = 0; k < 9; ++k) {
    const float2 ow0 = s_ow[sub][k][0], ow1 = s_ow[sub][k][1];
    const float2 ow2 = s_ow[sub][k][2], ow3 = s_ow[sub][k][3];
    float a[8] = {0.f, 0.f, 0.f, 0.f, 0.f, 0.f, 0.f, 0.f};
    acc8(xp4[(size_t)__float_as_int(ow0.x) + cid], ow0.y, a);
    acc8(xp4[(size_t)__float_as_int(ow1.x) + cid], ow1.y, a);
    acc8(xp4[(size_t)__float_as_int(ow2.x) + cid], ow2.y, a);
    acc8(xp4[(size_t)__float_as_int(ow3.x) + cid], ow3.y, a);
    uint4 o;
    o.x = pk2(a[0], a[1]); o.y = pk2(a[2], a[3]);
    o.z = pk2(a[4], a[5]); o.w = pk2(a[6], a[7]);
    ob[k * 32] = o;
  }
}

// ---------------- k_gemm: one px-chunk, 64(M)x128(N), 2-phase dbuf ----------------
// Grid (288,2)=576=2.25 blk/CU per chunk. XCD map matches k_sample's px partition so
// each XCD reads back the cols slice it wrote (L2/L3-hot). 4 waves, wave 32x64, acc[2][4].
__global__ __launch_bounds__(256) void k_gemm(const __hip_bfloat16* __restrict__ A,
                                              const __hip_bfloat16* __restrict__ Bt,
                                              const float* __restrict__ bias,
                                              float* __restrict__ out,
                                              int m_base) {
  __shared__ __align__(16) char lds[24576];   // 2 x {A [64][32] 4KB @0, B [128][32] 8KB @4096}

  const int tid  = threadIdx.x;
  const int xs   = (blockIdx.x & 7) * 36 + (blockIdx.x >> 3);   // XCD-contiguous in chunk
  const int m0   = xs * 64;                   // chunk-local row
  const int n0   = blockIdx.y * 128;
  const int lane = tid & 63, wave = tid >> 6;
  const int wm = wave >> 1, wn = wave & 1;    // 2M x 2N waves; wave tile 32M x 64N
  const int quad = lane >> 4, l16 = lane & 15;

  const int row = tid >> 2, kp = (tid & 3) ^ ((tid >> 3) & 3);
  const __hip_bfloat16* a0 = A  + (size_t)(m0 + row) * KC + kp * 8;
  const __hip_bfloat16* b0 = Bt + (size_t)(n0 + row) * KC + kp * 8;
  const __hip_bfloat16* b1 = b0 + (size_t)64 * KC;

  auto stage = [&](int buf, int k0) {
    char* base = &lds[buf * 12288];
    load_lds16(a0 + k0, base + tid * 16);
    load_lds16(b0 + k0, base + 4096 + tid * 16);
    load_lds16(b1 + k0, base + 8192 + tid * 16);
  };

  floatx4 acc[2][4];
#pragma unroll
  for (int i = 0; i < 2; ++i)
#pragma unroll
    for (int j = 0; j < 4; ++j) acc[i][j] = (floatx4){0.f, 0.f, 0.f, 0.f};

  const int swq = (quad ^ ((l16 >> 1) & 3)) * 16;

  stage(0, 0);
  int cur = 0;
#pragma unroll 1
  for (int k0 = 0; k0 < KC; k0 += 32) {
    __syncthreads();                       // drains stage issued last iter (or prologue)
    if (k0 + 32 < KC) stage(cur ^ 1, k0 + 32);
    const char* base = &lds[cur * 12288];

    bf16x8 af[2], bfr[4];
#pragma unroll
    for (int mt = 0; mt < 2; ++mt)
      af[mt] = *(const bf16x8*)&base[(wm * 32 + mt * 16 + l16) * 64 + swq];
#pragma unroll
    for (int nt = 0; nt < 4; ++nt)
      bfr[nt] = *(const bf16x8*)&base[4096 + (wn * 64 + nt * 16 + l16) * 64 + swq];
#pragma unroll
    for (int mt = 0; mt < 2; ++mt)
#pragma unroll
      for (int nt = 0; nt < 4; ++nt)
        acc[mt][nt] = __builtin_amdgcn_mfma_f32_16x16x32_bf16(af[mt], bfr[nt], acc[mt][nt], 0, 0, 0);
    cur ^= 1;
  }

#pragma unroll
  for (int mt = 0; mt < 2; ++mt) {
#pragma unroll
    for (int nt = 0; nt < 4; ++nt) {
      const int gm = m_base + m0 + wm * 32 + mt * 16 + quad * 4;
      const int gn = n0 + wn * 64 + nt * 16 + l16;
      const float bs = bias[gn];
#pragma unroll
      for (int r = 0; r < 4; ++r)
        out[(size_t)(gm + r) * F + gn] = acc[mt][nt][r] + bs;
    }
  }
}

extern "C" void kernel_launch(void* const* d_in, const int* in_sizes, int n_in,
                              void* d_out, int out_size, void* d_ws, size_t ws_size,
                              hipStream_t stream) {
  const float* x    = (const float*)d_in[0];   // [4,96,96,256]
  const float* omk  = (const float*)d_in[1];   // [3,3,256,27]
  const float* omb  = (const float*)d_in[2];   // [27]
  const float* kern = (const float*)d_in[3];   // [2304,256]
  const float* bias = (const float*)d_in[4];   // [256]
  float* out = (float*)d_out;                  // [4,96,96,256]

  char* ws = (char*)d_ws;
  size_t off = 0;
  __hip_bfloat16* wt   = (__hip_bfloat16*)(ws + off); off += (size_t)F * KC * 2;           // 1,179,648
  __hip_bfloat16* xp   = (__hip_bfloat16*)(ws + off); off += (size_t)4 * HP * HP * C * 2;  // 19,668,992
  __hip_bfloat16* wom  = (__hip_bfloat16*)(ws + off); off += (size_t)32 * KC * 2;          // 147,456
  float*          pOm  = (float*)(ws + off);          off += (size_t)NP * 32 * 4;          // 4,718,592
  __hip_bfloat16* colsC = (__hip_bfloat16*)(ws + off);                                     // 84,934,656 (aliased per chunk)

  k_prep  <<<dim3(NB_PAD + NB_OMW + NB_WT), 256, 0, stream>>>(x, omk, kern, (uint4*)xp, wom, wt);
  k_omgemm<<<dim3(576),                     256, 0, stream>>>(xp, wom, pOm);
#pragma unroll
  for (int c = 0; c < 2; ++c) {
    k_sample<<<dim3(NPC / 8),   256, 0, stream>>>((const uint4*)xp, pOm, omb, (uint4*)colsC, c * NPC);
    k_gemm  <<<dim3(288, 2),    256, 0, stream>>>(colsC, wt, bias, out, c * NPC);
  }
}

// Round 9
// 227.538 us; speedup vs baseline: 1.0437x; 1.0437x over previous
//
#include <hip/hip_runtime.h>
#include <hip/hip_bf16.h>
#include <stdint.h>
#include <stddef.h>

// DCNv2 forward: B=4, H=W=96, C=256, F=256, K=9 (3x3, same, stride1, dil1), DG=1.
// R5/R8/R11: fusion failed 3x. R7: swizzle (conflicts->0). R9: XCD swizzle (-5us).
// R10: 3-deep counted-vmcnt regressed. R12: atomic-free k_omgemm -> 213us BEST.
// R13: full-N k_gemm regressed (B-restage). R14: chunked producer->consumer regressed
//   (FETCH 46x2=92MB == R12's 87 -> no L3 retention to be had; but exposed invariant:
//   k_gemm cost ~1.2ns per block-ITERATION across configs -> window-count-bound).
// R15: revert to R12 config; k_gemm BK=64: 36 iterations (half the latency windows),
//   24 MFMA/wave/window (double fill). LDS 2x28KB=56KB (2 blk/CU). 128B rows use
//   8-slot XOR swizzle: stage global chunk (tid&7)^((tid>>3)&7) (same 128B segment
//   per 8 lanes), reads XOR (l16&7)<<4 (loop-invariant, bank-balanced).

namespace {
constexpr int H  = 96, W = 96, C = 256, F = 256;
constexpr int HP = 98;            // padded spatial dim (1-px zero halo)
constexpr int NP = 4 * 96 * 96;   // 36864 output pixels
constexpr int KC = 9 * 256;       // 2304 = GEMM K

constexpr int NB_PAD  = 4 * HP * HP / 8;       // 4802 blocks, 8 px each
constexpr int NB_OMW  = 9 * 32;                // 288
constexpr int NB_WT   = (KC / 64) * (F / 64);  // 144
}

typedef __attribute__((ext_vector_type(8))) short bf16x8;
typedef __attribute__((ext_vector_type(4))) float floatx4;

__device__ __forceinline__ void load_lds16(const void* g, void* l) {
  __builtin_amdgcn_global_load_lds((const __attribute__((address_space(1))) void*)g,
                                   (__attribute__((address_space(3))) void*)l,
                                   16, 0, 0);
}

__device__ __forceinline__ uint32_t pk2(float lo, float hi) {   // v_cvt_pk_bf16_f32 (RNE)
  __hip_bfloat162 t = __float22bfloat162_rn(float2{lo, hi});
  return *reinterpret_cast<uint32_t*>(&t);
}

__device__ __forceinline__ void acc8(uint4 v, float w, float* a) {
  a[0] += w * __uint_as_float(v.x << 16); a[1] += w * __uint_as_float(v.x & 0xffff0000u);
  a[2] += w * __uint_as_float(v.y << 16); a[3] += w * __uint_as_float(v.y & 0xffff0000u);
  a[4] += w * __uint_as_float(v.z << 16); a[5] += w * __uint_as_float(v.z & 0xffff0000u);
  a[6] += w * __uint_as_float(v.w << 16); a[7] += w * __uint_as_float(v.w & 0xffff0000u);
}

// ---------------- k_pad: x fp32 -> xp bf16 with 1-px zero halo ----------------
__global__ __launch_bounds__(256) void k_pad(const float* __restrict__ x,
                                             uint4* __restrict__ xp4) {
  const int tid = threadIdx.x;
  const int sub = tid >> 5, cid = tid & 31;
  const int pp  = blockIdx.x * 8 + sub;
  const int b   = pp / (HP * HP);
  const int r   = pp % (HP * HP);
  const int y   = r / HP, xq = r % HP;
  uint4 o = {0u, 0u, 0u, 0u};
  if (y >= 1 && y <= H && xq >= 1 && xq <= W) {
    const float* src = x + ((size_t)((b * H + (y - 1)) * W + (xq - 1))) * C + cid * 8;
    const float4 v0 = *(const float4*)src;
    const float4 v1 = *(const float4*)(src + 4);
    o.x = pk2(v0.x, v0.y); o.y = pk2(v0.z, v0.w);
    o.z = pk2(v1.x, v1.y); o.w = pk2(v1.z, v1.w);
  }
  xp4[(size_t)pp * 32 + cid] = o;
}

// ---------------- k_wprep: omw repack + wt transpose ----------------
__global__ __launch_bounds__(256) void k_wprep(const float* __restrict__ omk,
                                               const float* __restrict__ kern,
                                               __hip_bfloat16* __restrict__ wom,
                                               __hip_bfloat16* __restrict__ wt) {
  __shared__ float t[64][65];
  const int bi = blockIdx.x, tid = threadIdx.x;

  if (bi < NB_OMW) {                       // ---- omw: [9*256][27] -> [32][2304] ----
    const int kk = bi / 32, oc = bi % 32;
    float v = (oc < 27) ? omk[(size_t)(kk * 256 + tid) * 27 + oc] : 0.f;
    wom[(size_t)oc * KC + kk * 256 + tid] = __float2bfloat16(v);
  } else {                                 // ---- wt: [KC][F] -> [F][KC] bf16 ----
    const int j   = bi - NB_OMW;
    const int kc0 = (j % (KC / 64)) * 64, f0 = (j / (KC / 64)) * 64;
    const int rr = tid >> 6, cc = tid & 63;
#pragma unroll
    for (int i = 0; i < 16; ++i)
      t[rr * 16 + i][cc] = kern[(size_t)(kc0 + rr * 16 + i) * F + f0 + cc];
    __syncthreads();
#pragma unroll
    for (int i = 0; i < 16; ++i) {
      const int frow = rr * 16 + i;
      wt[(size_t)(f0 + frow) * KC + kc0 + cc] = __float2bfloat16(t[cc][frow]);
    }
  }
}

// ---------------- k_omgemm: implicit-im2col MFMA GEMM, 64(M)x32(N), full K, no atomics ----
__global__ __launch_bounds__(256) void k_omgemm(const __hip_bfloat16* __restrict__ xp,
                                                const __hip_bfloat16* __restrict__ wom,
                                                float* __restrict__ pOm) {
  __shared__ __align__(16) char lds[12288];   // 2 x {A [64][32] 4KB, B [32][32] 2KB}
  const int tid  = threadIdx.x;
  const int xr   = blockIdx.x;
  const int xs   = (xr & 7) * 72 + (xr >> 3);     // XCD-contiguous over 576 tiles
  const int m0   = xs * 64;
  const int lane = tid & 63, wave = tid >> 6;
  const int quad = lane >> 4, l16 = lane & 15;

  const int kp  = (tid & 3) ^ ((tid >> 3) & 3);
  const int row = tid >> 2;
  const int p  = m0 + row;
  const int b  = p / (H * W);
  const int hw = p % (H * W);
  const int h  = hw / W, w = hw % W;
  const __hip_bfloat16* abase = xp + ((size_t)(b * HP + h) * HP + w) * C + kp * 8;
  const __hip_bfloat16* bbase = wom + (size_t)row * KC + kp * 8;   // valid for tid<128

  auto stage = [&](int buf, int k0) {
    const int kk = k0 >> 8, c0 = k0 & 255;
    const int aoff = ((kk / 3) * HP + (kk % 3)) * C + c0;
    char* base = &lds[buf * 6144];
    load_lds16(abase + aoff, base + tid * 16);
    if (tid < 128) load_lds16(bbase + k0, base + 4096 + tid * 16);
  };

  floatx4 acc[2];
  acc[0] = (floatx4){0.f, 0.f, 0.f, 0.f};
  acc[1] = (floatx4){0.f, 0.f, 0.f, 0.f};

  const int swq = (quad ^ ((l16 >> 1) & 3)) * 16;

  stage(0, 0);
  int cur = 0;
#pragma unroll 1
  for (int k0 = 0; k0 < KC; k0 += 32) {
    __syncthreads();                       // drains stage issued last iter (or prologue)
    if (k0 + 32 < KC) stage(cur ^ 1, k0 + 32);
    const char* base = &lds[cur * 6144];

    bf16x8 af = *(const bf16x8*)&base[(wave * 16 + l16) * 64 + swq];
    bf16x8 b0 = *(const bf16x8*)&base[4096 + (l16) * 64 + swq];
    bf16x8 b1 = *(const bf16x8*)&base[4096 + (16 + l16) * 64 + swq];
    acc[0] = __builtin_amdgcn_mfma_f32_16x16x32_bf16(af, b0, acc[0], 0, 0, 0);
    acc[1] = __builtin_amdgcn_mfma_f32_16x16x32_bf16(af, b1, acc[1], 0, 0, 0);
    cur ^= 1;
  }

#pragma unroll
  for (int nt = 0; nt < 2; ++nt) {
    const int gm = m0 + wave * 16 + quad * 4;
    const int gn = nt * 16 + l16;
#pragma unroll
    for (int r = 0; r < 4; ++r)
      pOm[(size_t)(gm + r) * 32 + gn] = acc[nt][r];
  }
}

// ---------------- k_sample: 8 px/block, 8 ch/thread via uint4 full-line gathers ----------------
__global__ __launch_bounds__(256) void k_sample(const uint4* __restrict__ xp4,
                                                const float* __restrict__ pOm,
                                                const float* __restrict__ om_bias,
                                                uint4* __restrict__ cols4) {
  __shared__ float2 s_ow[8][9][4];   // per (px,k,corner): {uint4-offset, weight*mask}

  const int tid = threadIdx.x;
  const int sub = tid >> 5, cid = tid & 31;     // px-in-block, 8-ch unit
  const int bs  = (blockIdx.x & 7) * 576 + (blockIdx.x >> 3);   // XCD-contiguous

  if (tid < 72) {                               // setup: 8 px x 9 k
    const int ps = tid / 9, k = tid % 9;
    const int p  = bs * 8 + ps;
    const int b  = p / (H * W);
    const int hw = p % (H * W);
    const int h = hw / W, w = hw % W;
    const float dy = om_bias[2 * k]     + pOm[(size_t)p * 32 + 2 * k];
    const float dx = om_bias[2 * k + 1] + pOm[(size_t)p * 32 + 2 * k + 1];
    const float mv = om_bias[18 + k]    + pOm[(size_t)p * 32 + 18 + k];
    const float m  = 2.f / (1.f + __expf(-mv));
    const float sy = (float)(h - 1 + k / 3) + dy;
    const float sx = (float)(w - 1 + k % 3) + dx;
    const float y0f = floorf(sy), x0f = floorf(sx);
    const float fy = sy - y0f, fx = sx - x0f;
    const int y0 = (int)y0f, x0 = (int)x0f;
#pragma unroll
    for (int c2 = 0; c2 < 4; ++c2) {
      const int dy2 = c2 >> 1, dx2 = c2 & 1;
      const int yi = y0 + dy2, xi = x0 + dx2;
      const bool valid = (yi >= 0) & (yi < H) & (xi >= 0) & (xi < W);
      const float wgt = valid ? (dy2 ? fy : 1.f - fy) * (dx2 ? fx : 1.f - fx) * m : 0.f;
      const int yc = min(max(yi + 1, 0), HP - 1);
      const int xc = min(max(xi + 1, 0), HP - 1);
      const int off = ((b * HP + yc) * HP + xc) * 32;   // uint4 units
      s_ow[ps][k][c2] = float2{__int_as_float(off), wgt};
    }
  }
  __syncthreads();

  const int p = bs * 8 + sub;
  uint4* __restrict__ ob = cols4 + (size_t)p * 288 + cid;   // KC bf16 = 288 uint4/row

#pragma unroll 1
  for (int k = 0; k < 9; ++k) {
    const float2 ow0 = s_ow[sub][k][0], ow1 = s_ow[sub][k][1];
    const float2 ow2 = s_ow[sub][k][2], ow3 = s_ow[sub][k][3];
    float a[8] = {0.f, 0.f, 0.f, 0.f, 0.f, 0.f, 0.f, 0.f};
    acc8(xp4[(size_t)__float_as_int(ow0.x) + cid], ow0.y, a);
    acc8(xp4[(size_t)__float_as_int(ow1.x) + cid], ow1.y, a);
    acc8(xp4[(size_t)__float_as_int(ow2.x) + cid], ow2.y, a);
    acc8(xp4[(size_t)__float_as_int(ow3.x) + cid], ow3.y, a);
    uint4 o;
    o.x = pk2(a[0], a[1]); o.y = pk2(a[2], a[3]);
    o.z = pk2(a[4], a[5]); o.w = pk2(a[6], a[7]);
    ob[k * 32] = o;
  }
}

// ---------------- k_gemm: 96(M) x 128(N), BK=64 (36 windows), 2-phase dbuf ----------------
// Stage: 7 loads/thread/iter. A rows 0..95 / B rows 0..127, each row 128B staged by
// 8 threads with chunk-XOR (tid&7)^((tid>>3)&7) (same 128B segment -> coalesced).
// Reads: fragment chunk XOR (l16&7)<<4, loop-invariant, bank-balanced (8 lanes/slot).
__global__ __launch_bounds__(256) void k_gemm(const __hip_bfloat16* __restrict__ A,
                                              const __hip_bfloat16* __restrict__ Bt,
                                              const float* __restrict__ bias,
                                              float* __restrict__ out) {
  __shared__ __align__(16) char lds[57344];   // 2 x {A [96][64]bf16 12KB @0, B [128][64] 16KB @12288}

  const int tid  = threadIdx.x;
  const int m0   = blockIdx.x * 96;
  const int n0   = blockIdx.y * 128;
  const int lane = tid & 63, wave = tid >> 6;
  const int wm = wave & 1, wn = wave >> 1;    // wave = 48M x 64N
  const int quad = lane >> 4, l16 = lane & 15;

  const int srow = tid >> 3;                          // 0..31
  const int schk = (tid & 7) ^ (srow & 7);            // pre-swizzled source chunk
  const __hip_bfloat16* asrc = A  + (size_t)(m0 + srow) * KC + schk * 8;
  const __hip_bfloat16* bsrc = Bt + (size_t)(n0 + srow) * KC + schk * 8;

  auto stage = [&](int buf, int k0) {
    char* base = &lds[buf * 28672];
#pragma unroll
    for (int j = 0; j < 3; ++j)      // A rows 32j + srow
      load_lds16(asrc + (size_t)(32 * j) * KC + k0, base + j * 4096 + tid * 16);
#pragma unroll
    for (int j = 0; j < 4; ++j)      // B rows 32j + srow
      load_lds16(bsrc + (size_t)(32 * j) * KC + k0, base + 12288 + j * 4096 + tid * 16);
  };

  floatx4 acc[3][4];
#pragma unroll
  for (int i = 0; i < 3; ++i)
#pragma unroll
    for (int j = 0; j < 4; ++j) acc[i][j] = (floatx4){0.f, 0.f, 0.f, 0.f};

  const int swc = (l16 & 7) << 4;   // read-side chunk XOR (bytes)

  stage(0, 0);
  int cur = 0;
#pragma unroll 1
  for (int k0 = 0; k0 < KC; k0 += 64) {
    __syncthreads();                       // drains stage issued last iter (or prologue)
    if (k0 + 64 < KC) stage(cur ^ 1, k0 + 64);
    const char* base = &lds[cur * 28672];

#pragma unroll
    for (int kh = 0; kh < 2; ++kh) {
      const int co = (kh * 64 + quad * 16) ^ swc;
      bf16x8 af[3], bfr[4];
#pragma unroll
      for (int mt = 0; mt < 3; ++mt)
        af[mt] = *(const bf16x8*)&base[(wm * 48 + mt * 16 + l16) * 128 + co];
#pragma unroll
      for (int nt = 0; nt < 4; ++nt)
        bfr[nt] = *(const bf16x8*)&base[12288 + (wn * 64 + nt * 16 + l16) * 128 + co];
#pragma unroll
      for (int mt = 0; mt < 3; ++mt)
#pragma unroll
        for (int nt = 0; nt < 4; ++nt)
          acc[mt][nt] = __builtin_amdgcn_mfma_f32_16x16x32_bf16(af[mt], bfr[nt], acc[mt][nt], 0, 0, 0);
    }
    cur ^= 1;
  }

#pragma unroll
  for (int mt = 0; mt < 3; ++mt) {
#pragma unroll
    for (int nt = 0; nt < 4; ++nt) {
      const int gm = m0 + wm * 48 + mt * 16 + quad * 4;
      const int gn = n0 + wn * 64 + nt * 16 + l16;
      const float bs = bias[gn];
#pragma unroll
      for (int r = 0; r < 4; ++r)
        out[(size_t)(gm + r) * F + gn] = acc[mt][nt][r] + bs;
    }
  }
}

extern "C" void kernel_launch(void* const* d_in, const int* in_sizes, int n_in,
                              void* d_out, int out_size, void* d_ws, size_t ws_size,
                              hipStream_t stream) {
  const float* x    = (const float*)d_in[0];   // [4,96,96,256]
  const float* omk  = (const float*)d_in[1];   // [3,3,256,27]
  const float* omb  = (const float*)d_in[2];   // [27]
  const float* kern = (const float*)d_in[3];   // [2304,256]
  const float* bias = (const float*)d_in[4];   // [256]
  float* out = (float*)d_out;                  // [4,96,96,256]

  char* ws = (char*)d_ws;
  size_t off = 0;
  __hip_bfloat16* wt   = (__hip_bfloat16*)(ws + off); off += (size_t)F * KC * 2;           // 1,179,648
  __hip_bfloat16* xp   = (__hip_bfloat16*)(ws + off); off += (size_t)4 * HP * HP * C * 2;  // 19,668,992
  __hip_bfloat16* wom  = (__hip_bfloat16*)(ws + off); off += (size_t)32 * KC * 2;          // 147,456
  float*          pOm  = (float*)(ws + off);          off += (size_t)NP * 32 * 4;          // 4,718,592
  __hip_bfloat16* cols = (__hip_bfloat16*)(ws + off);                                      // 169,869,312

  k_pad   <<<dim3(NB_PAD),           256, 0, stream>>>(x, (uint4*)xp);
  k_wprep <<<dim3(NB_OMW + NB_WT),   256, 0, stream>>>(omk, kern, wom, wt);
  k_omgemm<<<dim3(576),              256, 0, stream>>>(xp, wom, pOm);
  k_sample<<<dim3(NP / 8),           256, 0, stream>>>((const uint4*)xp, pOm, omb, (uint4*)cols);
  k_gemm  <<<dim3(NP / 96, F / 128), 256, 0, stream>>>(cols, wt, bias, out);
}

// Round 10
// 201.405 us; speedup vs baseline: 1.1791x; 1.1298x over previous
//
#include <hip/hip_runtime.h>
#include <hip/hip_bf16.h>
#include <stdint.h>
#include <stddef.h>

// DCNv2 forward: B=4, H=W=96, C=256, F=256, K=9 (3x3, same, stride1, dil1), DG=1.
// R5/R8/R11: fusion failed 3x. R7: swizzle (conflicts->0). R9: XCD swizzle (-5us).
// R10/R13/R14/R15: k_gemm restructures all regressed -> R12 config (96x128, BK=32,
//   28KB, 2-phase) is k_gemm's plateau. R15 lesson: window-halving loses when it
//   perturbs cache timing of a STREAMED input (FETCH 87->145MB).
// R16: (a) k_omgemm BK=128: 72->18 windows (R14 invariant ~1.2ns/block-iter predicts
//   ~50->~15us); input xp is L2-resident so R15's failure mode can't apply. 16-slot
//   XOR swizzle for 256B rows (stage chunk slot^srow, read slot (ks*4+quad)^l16).
//   (b) k_gemm: R12 config + paired-N XCD map (u=(bid&7)*96+(bid>>3); m0=(u>>1)*96,
//   n0=(u&1)*128): the 2 blocks sharing an A-panel (442KB < 4MB L2) run adjacent on
//   the same XCD -> second cols read L2-hot. Predict k_gemm FETCH 87.6->~55MB.

namespace {
constexpr int H  = 96, W = 96, C = 256, F = 256;
constexpr int HP = 98;            // padded spatial dim (1-px zero halo)
constexpr int NP = 4 * 96 * 96;   // 36864 output pixels
constexpr int KC = 9 * 256;       // 2304 = GEMM K

constexpr int NB_PAD  = 4 * HP * HP / 8;       // 4802 blocks, 8 px each
constexpr int NB_OMW  = 9 * 32;                // 288
constexpr int NB_WT   = (KC / 64) * (F / 64);  // 144
}

typedef __attribute__((ext_vector_type(8))) short bf16x8;
typedef __attribute__((ext_vector_type(4))) float floatx4;

__device__ __forceinline__ void load_lds16(const void* g, void* l) {
  __builtin_amdgcn_global_load_lds((const __attribute__((address_space(1))) void*)g,
                                   (__attribute__((address_space(3))) void*)l,
                                   16, 0, 0);
}

__device__ __forceinline__ uint32_t pk2(float lo, float hi) {   // v_cvt_pk_bf16_f32 (RNE)
  __hip_bfloat162 t = __float22bfloat162_rn(float2{lo, hi});
  return *reinterpret_cast<uint32_t*>(&t);
}

__device__ __forceinline__ void acc8(uint4 v, float w, float* a) {
  a[0] += w * __uint_as_float(v.x << 16); a[1] += w * __uint_as_float(v.x & 0xffff0000u);
  a[2] += w * __uint_as_float(v.y << 16); a[3] += w * __uint_as_float(v.y & 0xffff0000u);
  a[4] += w * __uint_as_float(v.z << 16); a[5] += w * __uint_as_float(v.z & 0xffff0000u);
  a[6] += w * __uint_as_float(v.w << 16); a[7] += w * __uint_as_float(v.w & 0xffff0000u);
}

// ---------------- k_pad: x fp32 -> xp bf16 with 1-px zero halo ----------------
__global__ __launch_bounds__(256) void k_pad(const float* __restrict__ x,
                                             uint4* __restrict__ xp4) {
  const int tid = threadIdx.x;
  const int sub = tid >> 5, cid = tid & 31;
  const int pp  = blockIdx.x * 8 + sub;
  const int b   = pp / (HP * HP);
  const int r   = pp % (HP * HP);
  const int y   = r / HP, xq = r % HP;
  uint4 o = {0u, 0u, 0u, 0u};
  if (y >= 1 && y <= H && xq >= 1 && xq <= W) {
    const float* src = x + ((size_t)((b * H + (y - 1)) * W + (xq - 1))) * C + cid * 8;
    const float4 v0 = *(const float4*)src;
    const float4 v1 = *(const float4*)(src + 4);
    o.x = pk2(v0.x, v0.y); o.y = pk2(v0.z, v0.w);
    o.z = pk2(v1.x, v1.y); o.w = pk2(v1.z, v1.w);
  }
  xp4[(size_t)pp * 32 + cid] = o;
}

// ---------------- k_wprep: omw repack + wt transpose ----------------
__global__ __launch_bounds__(256) void k_wprep(const float* __restrict__ omk,
                                               const float* __restrict__ kern,
                                               __hip_bfloat16* __restrict__ wom,
                                               __hip_bfloat16* __restrict__ wt) {
  __shared__ float t[64][65];
  const int bi = blockIdx.x, tid = threadIdx.x;

  if (bi < NB_OMW) {                       // ---- omw: [9*256][27] -> [32][2304] ----
    const int kk = bi / 32, oc = bi % 32;
    float v = (oc < 27) ? omk[(size_t)(kk * 256 + tid) * 27 + oc] : 0.f;
    wom[(size_t)oc * KC + kk * 256 + tid] = __float2bfloat16(v);
  } else {                                 // ---- wt: [KC][F] -> [F][KC] bf16 ----
    const int j   = bi - NB_OMW;
    const int kc0 = (j % (KC / 64)) * 64, f0 = (j / (KC / 64)) * 64;
    const int rr = tid >> 6, cc = tid & 63;
#pragma unroll
    for (int i = 0; i < 16; ++i)
      t[rr * 16 + i][cc] = kern[(size_t)(kc0 + rr * 16 + i) * F + f0 + cc];
    __syncthreads();
#pragma unroll
    for (int i = 0; i < 16; ++i) {
      const int frow = rr * 16 + i;
      wt[(size_t)(f0 + frow) * KC + kc0 + cc] = __float2bfloat16(t[cc][frow]);
    }
  }
}

// ---------------- k_omgemm: 64(M)x32(N), BK=128 -> 18 windows, 2-phase dbuf ----------------
// LDS 2 x {A [64][128]bf16 16KB, B [32][128] 8KB} = 48KB (3 blk/CU >= 2.25 grid).
// 256B rows, 16-slot XOR swizzle: stage thread (srow=tid>>4, slot=tid&15) fetches
// global chunk slot^srow (same 256B segment per 16 thr -> coalesced; LDS dest linear).
// Read: slot ((ks*4+quad)^l16)*16B -- uniform 4 lanes/chunk, conflict-free.
__global__ __launch_bounds__(256) void k_omgemm(const __hip_bfloat16* __restrict__ xp,
                                                const __hip_bfloat16* __restrict__ wom,
                                                float* __restrict__ pOm) {
  __shared__ __align__(16) char lds[49152];
  const int tid  = threadIdx.x;
  const int xr   = blockIdx.x;
  const int xs   = (xr & 7) * 72 + (xr >> 3);     // XCD-contiguous over 576 tiles
  const int m0   = xs * 64;
  const int lane = tid & 63, wave = tid >> 6;
  const int quad = lane >> 4, l16 = lane & 15;

  const int srow = tid >> 4;          // 0..15
  const int gchk = (tid & 15) ^ srow; // pre-swizzled global chunk (16B units)

  const __hip_bfloat16* abase[4];
#pragma unroll
  for (int j = 0; j < 4; ++j) {
    const int p  = m0 + srow + j * 16;
    const int b  = p / (H * W);
    const int hw = p % (H * W);
    const int h  = hw / W, w = hw % W;
    abase[j] = xp + ((size_t)(b * HP + h) * HP + w) * C + gchk * 8;
  }
  const __hip_bfloat16* bbase[2];
#pragma unroll
  for (int j = 0; j < 2; ++j)
    bbase[j] = wom + (size_t)(srow + j * 16) * KC + gchk * 8;

  auto stage = [&](int buf, int k0) {
    const int kk = k0 >> 8, c0 = k0 & 255;
    const int aoff = ((kk / 3) * HP + (kk % 3)) * C + c0;
    char* base = &lds[buf * 24576];
#pragma unroll
    for (int j = 0; j < 4; ++j)                 // A rows srow + 16j
      load_lds16(abase[j] + aoff, base + j * 4096 + tid * 16);
#pragma unroll
    for (int j = 0; j < 2; ++j)                 // B rows srow + 16j
      load_lds16(bbase[j] + k0, base + 16384 + j * 4096 + tid * 16);
  };

  floatx4 acc[2];
  acc[0] = (floatx4){0.f, 0.f, 0.f, 0.f};
  acc[1] = (floatx4){0.f, 0.f, 0.f, 0.f};

  stage(0, 0);
  int cur = 0;
#pragma unroll 1
  for (int k0 = 0; k0 < KC; k0 += 128) {
    __syncthreads();                       // drains stage issued last iter (or prologue)
    if (k0 + 128 < KC) stage(cur ^ 1, k0 + 128);
    const char* base = &lds[cur * 24576];

#pragma unroll
    for (int ks = 0; ks < 4; ++ks) {
      const int slot = (((ks * 4 + quad) ^ l16) & 15) * 16;   // byte offset in 256B row
      bf16x8 af = *(const bf16x8*)&base[(wave * 16 + l16) * 256 + slot];
      bf16x8 b0 = *(const bf16x8*)&base[16384 + l16 * 256 + slot];
      bf16x8 b1 = *(const bf16x8*)&base[16384 + (16 + l16) * 256 + slot];
      acc[0] = __builtin_amdgcn_mfma_f32_16x16x32_bf16(af, b0, acc[0], 0, 0, 0);
      acc[1] = __builtin_amdgcn_mfma_f32_16x16x32_bf16(af, b1, acc[1], 0, 0, 0);
    }
    cur ^= 1;
  }

#pragma unroll
  for (int nt = 0; nt < 2; ++nt) {
    const int gm = m0 + wave * 16 + quad * 4;
    const int gn = nt * 16 + l16;
#pragma unroll
    for (int r = 0; r < 4; ++r)
      pOm[(size_t)(gm + r) * 32 + gn] = acc[nt][r];
  }
}

// ---------------- k_sample: 8 px/block, 8 ch/thread via uint4 full-line gathers ----------------
__global__ __launch_bounds__(256) void k_sample(const uint4* __restrict__ xp4,
                                                const float* __restrict__ pOm,
                                                const float* __restrict__ om_bias,
                                                uint4* __restrict__ cols4) {
  __shared__ float2 s_ow[8][9][4];   // per (px,k,corner): {uint4-offset, weight*mask}

  const int tid = threadIdx.x;
  const int sub = tid >> 5, cid = tid & 31;     // px-in-block, 8-ch unit
  const int bs  = (blockIdx.x & 7) * 576 + (blockIdx.x >> 3);   // XCD-contiguous

  if (tid < 72) {                               // setup: 8 px x 9 k
    const int ps = tid / 9, k = tid % 9;
    const int p  = bs * 8 + ps;
    const int b  = p / (H * W);
    const int hw = p % (H * W);
    const int h = hw / W, w = hw % W;
    const float dy = om_bias[2 * k]     + pOm[(size_t)p * 32 + 2 * k];
    const float dx = om_bias[2 * k + 1] + pOm[(size_t)p * 32 + 2 * k + 1];
    const float mv = om_bias[18 + k]    + pOm[(size_t)p * 32 + 18 + k];
    const float m  = 2.f / (1.f + __expf(-mv));
    const float sy = (float)(h - 1 + k / 3) + dy;
    const float sx = (float)(w - 1 + k % 3) + dx;
    const float y0f = floorf(sy), x0f = floorf(sx);
    const float fy = sy - y0f, fx = sx - x0f;
    const int y0 = (int)y0f, x0 = (int)x0f;
#pragma unroll
    for (int c2 = 0; c2 < 4; ++c2) {
      const int dy2 = c2 >> 1, dx2 = c2 & 1;
      const int yi = y0 + dy2, xi = x0 + dx2;
      const bool valid = (yi >= 0) & (yi < H) & (xi >= 0) & (xi < W);
      const float wgt = valid ? (dy2 ? fy : 1.f - fy) * (dx2 ? fx : 1.f - fx) * m : 0.f;
      const int yc = min(max(yi + 1, 0), HP - 1);
      const int xc = min(max(xi + 1, 0), HP - 1);
      const int off = ((b * HP + yc) * HP + xc) * 32;   // uint4 units
      s_ow[ps][k][c2] = float2{__int_as_float(off), wgt};
    }
  }
  __syncthreads();

  const int p = bs * 8 + sub;
  uint4* __restrict__ ob = cols4 + (size_t)p * 288 + cid;   // KC bf16 = 288 uint4/row

#pragma unroll 1
  for (int k = 0; k < 9; ++k) {
    const float2 ow0 = s_ow[sub][k][0], ow1 = s_ow[sub][k][1];
    const float2 ow2 = s_ow[sub][k][2], ow3 = s_ow[sub][k][3];
    float a[8] = {0.f, 0.f, 0.f, 0.f, 0.f, 0.f, 0.f, 0.f};
    acc8(xp4[(size_t)__float_as_int(ow0.x) + cid], ow0.y, a);
    acc8(xp4[(size_t)__float_as_int(ow1.x) + cid], ow1.y, a);
    acc8(xp4[(size_t)__float_as_int(ow2.x) + cid], ow2.y, a);
    acc8(xp4[(size_t)__float_as_int(ow3.x) + cid], ow3.y, a);
    uint4 o;
    o.x = pk2(a[0], a[1]); o.y = pk2(a[2], a[3]);
    o.z = pk2(a[4], a[5]); o.w = pk2(a[6], a[7]);
    ob[k * 32] = o;
  }
}

// ---------------- k_gemm: 96(M)x128(N), BK=32, 2-phase (R12 config) + paired-N XCD map ----
// u=(bid&7)*96+(bid>>3); m0=(u>>1)*96, n0=(u&1)*128: both N-halves of an M-tile run
// adjacent on the same XCD -> A panel (442KB) L2-hot for the second block.
__global__ __launch_bounds__(256) void k_gemm(const __hip_bfloat16* __restrict__ A,
                                              const __hip_bfloat16* __restrict__ Bt,
                                              const float* __restrict__ bias,
                                              float* __restrict__ out) {
  __shared__ __align__(16) char lds[28672];   // 2 x {A [96][32] 6KB @0, B [128][32] 8KB @6144}

  const int tid  = threadIdx.x;
  const int u    = (blockIdx.x & 7) * 96 + (blockIdx.x >> 3);   // XCD-contiguous pair units
  const int m0   = (u >> 1) * 96;
  const int n0   = (u & 1) * 128;
  const int lane = tid & 63, wave = tid >> 6;
  const int wm = wave & 1, wn = wave >> 1;    // wave = 48M x 64N
  const int quad = lane >> 4, l16 = lane & 15;

  const int row = tid >> 2, kp = (tid & 3) ^ ((tid >> 3) & 3);
  const __hip_bfloat16* a0 = A  + (size_t)(m0 + row) * KC + kp * 8;
  const __hip_bfloat16* a1 = A  + (size_t)(m0 + 64 + row) * KC + kp * 8;   // tid<128
  const __hip_bfloat16* b0 = Bt + (size_t)(n0 + row) * KC + kp * 8;
  const __hip_bfloat16* b1 = Bt + (size_t)(n0 + 64 + row) * KC + kp * 8;

  auto stage = [&](int buf, int k0) {
    char* base = &lds[buf * 14336];
    load_lds16(a0 + k0, base + tid * 16);
    if (tid < 128) load_lds16(a1 + k0, base + 4096 + tid * 16);
    load_lds16(b0 + k0, base + 6144 + tid * 16);
    load_lds16(b1 + k0, base + 10240 + tid * 16);
  };

  floatx4 acc[3][4];
#pragma unroll
  for (int i = 0; i < 3; ++i)
#pragma unroll
    for (int j = 0; j < 4; ++j) acc[i][j] = (floatx4){0.f, 0.f, 0.f, 0.f};

  const int swq = (quad ^ ((l16 >> 1) & 3)) * 16;

  stage(0, 0);
  int cur = 0;
#pragma unroll 1
  for (int k0 = 0; k0 < KC; k0 += 32) {
    __syncthreads();                       // drains stage issued last iter (or prologue)
    if (k0 + 32 < KC) stage(cur ^ 1, k0 + 32);
    const char* base = &lds[cur * 14336];

    bf16x8 af[3], bfr[4];
#pragma unroll
    for (int mt = 0; mt < 3; ++mt)
      af[mt] = *(const bf16x8*)&base[(wm * 48 + mt * 16 + l16) * 64 + swq];
#pragma unroll
    for (int nt = 0; nt < 4; ++nt)
      bfr[nt] = *(const bf16x8*)&base[6144 + (wn * 64 + nt * 16 + l16) * 64 + swq];
#pragma unroll
    for (int mt = 0; mt < 3; ++mt)
#pragma unroll
      for (int nt = 0; nt < 4; ++nt)
        acc[mt][nt] = __builtin_amdgcn_mfma_f32_16x16x32_bf16(af[mt], bfr[nt], acc[mt][nt], 0, 0, 0);
    cur ^= 1;
  }

#pragma unroll
  for (int mt = 0; mt < 3; ++mt) {
#pragma unroll
    for (int nt = 0; nt < 4; ++nt) {
      const int gm = m0 + wm * 48 + mt * 16 + quad * 4;
      const int gn = n0 + wn * 64 + nt * 16 + l16;
      const float bs = bias[gn];
#pragma unroll
      for (int r = 0; r < 4; ++r)
        out[(size_t)(gm + r) * F + gn] = acc[mt][nt][r] + bs;
    }
  }
}

extern "C" void kernel_launch(void* const* d_in, const int* in_sizes, int n_in,
                              void* d_out, int out_size, void* d_ws, size_t ws_size,
                              hipStream_t stream) {
  const float* x    = (const float*)d_in[0];   // [4,96,96,256]
  const float* omk  = (const float*)d_in[1];   // [3,3,256,27]
  const float* omb  = (const float*)d_in[2];   // [27]
  const float* kern = (const float*)d_in[3];   // [2304,256]
  const float* bias = (const float*)d_in[4];   // [256]
  float* out = (float*)d_out;                  // [4,96,96,256]

  char* ws = (char*)d_ws;
  size_t off = 0;
  __hip_bfloat16* wt   = (__hip_bfloat16*)(ws + off); off += (size_t)F * KC * 2;           // 1,179,648
  __hip_bfloat16* xp   = (__hip_bfloat16*)(ws + off); off += (size_t)4 * HP * HP * C * 2;  // 19,668,992
  __hip_bfloat16* wom  = (__hip_bfloat16*)(ws + off); off += (size_t)32 * KC * 2;          // 147,456
  float*          pOm  = (float*)(ws + off);          off += (size_t)NP * 32 * 4;          // 4,718,592
  __hip_bfloat16* cols = (__hip_bfloat16*)(ws + off);                                      // 169,869,312

  k_pad   <<<dim3(NB_PAD),         256, 0, stream>>>(x, (uint4*)xp);
  k_wprep <<<dim3(NB_OMW + NB_WT), 256, 0, stream>>>(omk, kern, wom, wt);
  k_omgemm<<<dim3(576),            256, 0, stream>>>(xp, wom, pOm);
  k_sample<<<dim3(NP / 8),         256, 0, stream>>>((const uint4*)xp, pOm, omb, (uint4*)cols);
  k_gemm  <<<dim3(768),            256, 0, stream>>>(cols, wt, bias, out);
}